// Round 2
// baseline (7545.556 us; speedup 1.0000x reference)
//
#include <hip/hip_runtime.h>

// Sudoku solver, fully fused into ONE plain (non-cooperative) kernel.
// Cross-block sync = hand-rolled sense-reversing barrier in workspace
// (device-scope atomics + __threadfence), zeroed host-side via hipMemsetAsync.
// Grid 512 blocks x 128 thr: guaranteed co-resident (>=4 blocks/CU by
// __launch_bounds__(128,2), 8 by LDS) -> no deadlock risk, graph-capture safe.
// Phase bodies are bitwise-identical math to the verified 994us version:
//   init -> 4x { prep(+L1) -> 8x gemm -> final(softmax) -> update }

#define NN 81
#define ND 9
#define BTSZ 512
#define HD 512
#define NE_MAX 4
#define MSTRIDE 2048            // BTSZ * NE_MAX
#define XTOT (BTSZ * NN * ND)   // 373248
#define NBLK 512
#define TPB 128

#define SCOPE_AGENT __HIP_MEMORY_SCOPE_AGENT

struct Params {
  const float* x_in;
  const float* W[10];
  const float* Bb[10];
  const int* n_it;
  float* xpred;
  float* xcur;
  float* H0;
  float* H1;
  int* slotQ;
  int* slotB;
  int* boardBase;
  int* boardCount;
  float* slotMax;
  int* slotPos;
  int* cnt;   // cnt[0..3] per-iter slot counters; cnt[4]=arrive, cnt[5]=generation
};

__device__ __forceinline__ void gsync(int* bar) {
  __syncthreads();
  if (threadIdx.x == 0) {
    __threadfence();  // release: flush this XCD's prior stores device-wide
    const int gen = __hip_atomic_load(&bar[1], __ATOMIC_RELAXED, SCOPE_AGENT);
    const int arr =
        __hip_atomic_fetch_add(&bar[0], 1, __ATOMIC_ACQ_REL, SCOPE_AGENT);
    if (arr == NBLK - 1) {
      __hip_atomic_store(&bar[0], 0, __ATOMIC_RELAXED, SCOPE_AGENT);
      __hip_atomic_fetch_add(&bar[1], 1, __ATOMIC_RELEASE, SCOPE_AGENT);
    } else {
      while (__hip_atomic_load(&bar[1], __ATOMIC_ACQUIRE, SCOPE_AGENT) == gen) {
        __builtin_amdgcn_s_sleep(2);
      }
    }
    __threadfence();  // acquire: invalidate stale lines before proceeding
  }
  __syncthreads();
}

__global__ __launch_bounds__(TPB, 2) void fused(Params p) {
  const int tid = threadIdx.x;
  const int bid = blockIdx.x;
  const int gid = bid * TPB + tid;
  int* bar = p.cnt + 4;
  // shared pool, unioned across phases:
  //   prep : xs[729] | fs[4*27]@736 | eflag[81]@int848 | lst[4]@int932 | cnt,base@936
  //   gemm : As[32*32]@0, Bs[32*64]@1024
  //   final: Ws[512*9]@0
  __shared__ __align__(16) float smem[HD * ND];  // 4608 floats = 18 KB

  // ---------------- init ----------------
  for (int i = gid; i < XTOT; i += NBLK * TPB) {
    const float v = p.x_in[i];
    p.xpred[i] = v;
    p.xcur[i] = v;
  }
  const int nIters = p.n_it[0];
  gsync(bar);

  for (int it = 0; it < 4; ++it) {
    if (it >= nIters) break;  // uniform across grid

    // ---------------- prep: features + layer 1 (board = bid) ----------------
    {
      const int b = bid;
      float* xs = smem;           // 729
      float* fsb = smem + 736;    // 4*27
      int* ip = (int*)smem;
      int* eflag = ip + 848;      // 81
      int* lst = ip + 932;        // 4
      for (int i = tid; i < NN * ND; i += TPB) xs[i] = p.xcur[b * NN * ND + i];
      if (tid < NE_MAX * 27) fsb[tid] = 0.0f;
      __syncthreads();
      if (tid < NN) {
        float s = 0.f;
#pragma unroll
        for (int n = 0; n < ND; ++n) s += xs[tid * ND + n];
        eflag[tid] = (s == 0.0f) ? 1 : 0;
      }
      __syncthreads();
      if (tid == 0) {
        int c = 0;
        for (int q = 0; q < NN; ++q)
          if (eflag[q] && c < NE_MAX) lst[c++] = q;  // ascending q tie-break
        const int base0 = atomicAdd(&p.cnt[it], c);
        ip[936] = c;
        ip[937] = base0;
        p.boardCount[b] = c;
        p.boardBase[b] = base0;
      }
      __syncthreads();
      const int cc = ip[936], base = ip[937];
      if (tid < cc) {
        p.slotQ[base + tid] = lst[tid];
        p.slotB[base + tid] = b;
      }
      {
        const int fc = tid >> 5, u = tid & 31;
        if (fc < cc && u < 27) {
          const int q = lst[fc], t = u / 9, n = u % 9;
          const int r = q / 9, cl = q % 9;
          float s = 0.f;
          if (t == 0) {
            for (int i = 0; i < 9; ++i) s += xs[(r * 9 + i) * ND + n];
          } else if (t == 1) {
            for (int i = 0; i < 9; ++i) s += xs[(i * 9 + cl) * ND + n];
          } else {
            const int br = (r / 3) * 3, bc = (cl / 3) * 3;
            for (int i = 0; i < 3; ++i)
              for (int j = 0; j < 3; ++j) s += xs[((br + i) * 9 + bc + j) * ND + n];
          }
          fsb[fc * 27 + u] = s;
        }
      }
      __syncthreads();
      // layer 1: 128 threads x 4 outputs, same per-output i-order as before
      float a[4][NE_MAX];
#pragma unroll
      for (int o = 0; o < 4; ++o) {
        const float bb = p.Bb[0][tid + 128 * o];
#pragma unroll
        for (int c = 0; c < NE_MAX; ++c) a[o][c] = bb;
      }
      for (int i = 0; i < 27; ++i) {
        float w[4];
#pragma unroll
        for (int o = 0; o < 4; ++o) w[o] = p.W[0][i * HD + tid + 128 * o];
#pragma unroll
        for (int c = 0; c < NE_MAX; ++c) {
          const float f = fsb[c * 27 + i];
#pragma unroll
          for (int o = 0; o < 4; ++o) a[o][c] += f * w[o];
        }
      }
#pragma unroll
      for (int o = 0; o < 4; ++o)
#pragma unroll
        for (int c = 0; c < NE_MAX; ++c)
          if (c < cc)
            p.H0[(tid + 128 * o) * MSTRIDE + base + c] = fmaxf(a[o][c], 0.0f);
    }
    gsync(bar);

    const int M = p.cnt[it];
    const int Mt8 = ((M + 31) >> 5) << 3;  // Mtiles * 8 n-tiles
    const float* Ain = p.H0;
    float* Cout = p.H1;

    // ---------------- layers 2..9: tiled GEMM, K-major ----------------
    for (int l = 1; l <= 8; ++l) {
      const float* __restrict__ Wl = p.W[l];
      const float* __restrict__ bl = p.Bb[l];
      float* As = smem;         // [32][32]
      float* Bs = smem + 1024;  // [32][64]
      const int tx = tid & 15, ty = tid >> 4;
      const int la_k = tid >> 3, la_m = (tid & 7) << 2;
      const int lb_k = tid >> 4, lb_n = (tid & 15) << 2;
      for (int t = bid; t < Mt8; t += NBLK) {
        const int m0 = (t >> 3) << 5;
        const int n0 = (t & 7) << 6;
        float acc[4][4];
#pragma unroll
        for (int r = 0; r < 4; ++r)
#pragma unroll
          for (int c = 0; c < 4; ++c) acc[r][c] = 0.f;
        for (int kb = 0; kb < HD / 32; ++kb) {
          const int k0 = kb * 32;
          *(float4*)&As[la_k * 32 + la_m] =
              *(const float4*)&Ain[(k0 + la_k) * MSTRIDE + m0 + la_m];
          *(float4*)&As[(la_k + 16) * 32 + la_m] =
              *(const float4*)&Ain[(k0 + la_k + 16) * MSTRIDE + m0 + la_m];
#pragma unroll
          for (int i2 = 0; i2 < 4; ++i2)
            *(float4*)&Bs[(lb_k + 8 * i2) * 64 + lb_n] =
                *(const float4*)&Wl[(k0 + lb_k + 8 * i2) * HD + n0 + lb_n];
          __syncthreads();
#pragma unroll
          for (int kk = 0; kk < 32; ++kk) {
            const float4 av = *(const float4*)&As[kk * 32 + (ty << 2)];
            const float4 bv = *(const float4*)&Bs[kk * 64 + (tx << 2)];
            const float ar[4] = {av.x, av.y, av.z, av.w};
            const float br[4] = {bv.x, bv.y, bv.z, bv.w};
#pragma unroll
            for (int r = 0; r < 4; ++r)
#pragma unroll
              for (int c = 0; c < 4; ++c) acc[r][c] += ar[r] * br[c];
          }
          __syncthreads();
        }
        const int m = m0 + (ty << 2);
#pragma unroll
        for (int c = 0; c < 4; ++c) {
          const int j = n0 + (tx << 2) + c;
          const float bj = bl[j];
          float4 v;
          v.x = fmaxf(acc[0][c] + bj, 0.f);
          v.y = fmaxf(acc[1][c] + bj, 0.f);
          v.z = fmaxf(acc[2][c] + bj, 0.f);
          v.w = fmaxf(acc[3][c] + bj, 0.f);
          if (m + 3 < M) {
            *(float4*)&Cout[j * MSTRIDE + m] = v;
          } else {
            const float vv[4] = {v.x, v.y, v.z, v.w};
            for (int r = 0; r < 4; ++r)
              if (m + r < M) Cout[j * MSTRIDE + m + r] = vv[r];
          }
        }
      }
      gsync(bar);
      const float* tswap = Ain;
      Ain = Cout;
      Cout = (float*)tswap;
    }
    // after 8 swaps Ain == p.H0 (holds h9)

    // ---------------- final: layer 10 + softmax + slot max ----------------
    {
      for (int i = tid; i < HD * ND; i += TPB) smem[i] = p.W[9][i];
      __syncthreads();
      const int wv = tid >> 6, lane = tid & 63;
      for (int slot = bid * 2 + wv; slot < M; slot += NBLK * 2) {
        float acc[ND];
#pragma unroll
        for (int j = 0; j < ND; ++j) acc[j] = 0.f;
#pragma unroll
        for (int i = 0; i < 8; ++i) {
          const int k = lane + 64 * i;
          const float hv = Ain[k * MSTRIDE + slot];
#pragma unroll
          for (int j = 0; j < ND; ++j) acc[j] += hv * smem[k * ND + j];
        }
#pragma unroll
        for (int j = 0; j < ND; ++j) {
#pragma unroll
          for (int off = 32; off >= 1; off >>= 1)
            acc[j] += __shfl_xor(acc[j], off, 64);
        }
        if (lane == 0) {
          float lgt[ND];
#pragma unroll
          for (int j = 0; j < ND; ++j) lgt[j] = acc[j] + p.Bb[9][j];
          float mx = lgt[0];
          for (int j = 1; j < ND; ++j) mx = fmaxf(mx, lgt[j]);
          float e[ND], s = 0.f;
          for (int j = 0; j < ND; ++j) {
            e[j] = expf(lgt[j] - mx);
            s += e[j];
          }
          float pr[ND];
          for (int j = 0; j < ND; ++j) pr[j] = e[j] / s;
          const int b = p.slotB[slot], q = p.slotQ[slot];
          float best = pr[0];
          int pos = 0;
          for (int j = 1; j < ND; ++j)
            if (pr[j] > best) { best = pr[j]; pos = j; }  // first-index tie-break
          float* dst = p.xpred + (b * NN + q) * ND;
          for (int j = 0; j < ND; ++j) dst[j] = pr[j];
          p.slotMax[slot] = best;
          p.slotPos[slot] = pos;
        }
      }
    }
    gsync(bar);

    // ---------------- update: most confident cell per board ----------------
    if (gid < BTSZ) {
      const int b = gid;
      const int c = p.boardCount[b];
      if (c > 0) {
        const int base = p.boardBase[b];
        float best = p.slotMax[base];
        int bj = 0;
        for (int j = 1; j < c; ++j) {
          const float v = p.slotMax[base + j];
          if (v > best) { best = v; bj = j; }  // strict >: lowest q wins
        }
        const int q = p.slotQ[base + bj], pos = p.slotPos[base + bj];
        p.xcur[(b * NN + q) * ND + pos] = 1.0f;
      }
    }
    gsync(bar);
  }
}

extern "C" void kernel_launch(void* const* d_in, const int* in_sizes, int n_in,
                              void* d_out, int out_size, void* d_ws, size_t ws_size,
                              hipStream_t stream) {
  Params prm;
  prm.x_in = (const float*)d_in[0];
  for (int i = 0; i < 10; ++i) {
    prm.W[i] = (const float*)d_in[2 + 2 * i];
    prm.Bb[i] = (const float*)d_in[3 + 2 * i];
  }
  prm.n_it = (const int*)d_in[22];
  prm.xpred = (float*)d_out;
  prm.xcur = prm.xpred + XTOT;
  prm.H0 = (float*)d_ws;
  prm.H1 = prm.H0 + HD * MSTRIDE;
  prm.slotQ = (int*)(prm.H1 + HD * MSTRIDE);
  prm.slotB = prm.slotQ + MSTRIDE;
  prm.boardBase = prm.slotB + MSTRIDE;
  prm.boardCount = prm.boardBase + BTSZ;
  prm.slotMax = (float*)(prm.boardCount + BTSZ);
  prm.slotPos = (int*)(prm.slotMax + MSTRIDE);
  prm.cnt = prm.slotPos + MSTRIDE;

  // zero per-iter counters (cnt[0..3]) and barrier state (cnt[4..5])
  hipMemsetAsync(prm.cnt, 0, 8 * sizeof(int), stream);

  fused<<<dim3(NBLK), dim3(TPB), 0, stream>>>(prm);
}

// Round 3
// 1493.395 us; speedup vs baseline: 5.0526x; 5.0526x over previous
//
#include <hip/hip_runtime.h>

// Sudoku solver: ONE kernel, ZERO grid syncs.
// Key insight: boards are fully independent in the reference computation —
// the batch dimension never mixes. So each block owns 2 boards and runs the
// entire 4-iteration pipeline block-locally:
//   per iter: empties -> features -> L1 -> 8x GEMV(512x512) -> L10+softmax -> update
// Activations live in LDS (8 slots x 512, ping-pong). Weights stream from
// global: all 256 blocks read the same 1MB/layer concurrently -> L2-served
// (self-synchronizing: laggards get L2 hits and catch up).
// FMA accumulation order per output is IDENTICAL to the verified 994us
// baseline (ascending-k single chains, bias-then-relu, same final-layer
// lane+shuffle pattern) -> same argmax decisions, same absmax.

#define NN 81
#define ND 9
#define BND 729            // NN*ND
#define HD 512
#define NE_MAX 4
#define BTSZ 512
#define XTOT (BTSZ * BND)  // 373248
#define NBLK 256           // 2 boards per block
#define TPB 256

struct Params {
  const float* x_in;
  const float* W[10];
  const float* Bb[10];
  const int* n_it;
  float* xpred;
  float* xcur;
};

__global__ __launch_bounds__(TPB, 1) void fused(Params p) {
  const int tid = threadIdx.x;
  const int bid = blockIdx.x;
  const int b0 = bid * 2;

  __shared__ __align__(16) float hbuf[2][8 * HD];  // 32 KB ping-pong activations
  __shared__ __align__(16) float W10s[HD * ND];    // 18 KB final-layer weights
  __shared__ float xs[2][BND + 3];                 // board states
  __shared__ float fs[2][NE_MAX][28];              // features (27, padded)
  __shared__ float sMax[8];
  __shared__ int sPos[8];
  __shared__ int ef[2][NN + 7];
  __shared__ int lst[2][NE_MAX];
  __shared__ int eCnt[2];

  // stage W10 once (constant across iterations)
  for (int i = tid; i < HD * ND; i += TPB) W10s[i] = p.W[9][i];
  // load boards; init xpred = x
  for (int bd = 0; bd < 2; ++bd)
    for (int i = tid; i < BND; i += TPB) {
      const float v = p.x_in[(b0 + bd) * BND + i];
      xs[bd][i] = v;
      p.xpred[(b0 + bd) * BND + i] = v;
    }
  const int nIters = p.n_it[0];
  __syncthreads();

  const int j0 = tid * 2;  // each thread owns 2 output columns

  for (int it = 0; it < 4; ++it) {
    if (it >= nIters) break;

    // ---- empty flags ----
    if (tid < 2 * NN) {
      const int bd = tid / NN, q = tid - bd * NN;
      float s = 0.f;
#pragma unroll
      for (int n = 0; n < ND; ++n) s += xs[bd][q * ND + n];
      ef[bd][q] = (s == 0.0f) ? 1 : 0;
    }
    __syncthreads();
    if (tid < 2) {
      int c = 0;
      for (int q = 0; q < NN; ++q)
        if (ef[tid][q] && c < NE_MAX) lst[tid][c++] = q;  // ascending q
      eCnt[tid] = c;
    }
    __syncthreads();

    // ---- features (zero for inactive slots) ----
    {
      const int sl = tid >> 5, u = tid & 31;
      const int bd = sl >> 2, e = sl & 3;
      if (u < 28) fs[bd][e][u] = 0.0f;
      if (u < 27 && e < eCnt[bd]) {
        const int q = lst[bd][e], t = u / 9, n = u - t * 9;
        const int r = q / 9, cl = q - r * 9;
        float s = 0.f;
        if (t == 0) {
          for (int i = 0; i < 9; ++i) s += xs[bd][(r * 9 + i) * ND + n];
        } else if (t == 1) {
          for (int i = 0; i < 9; ++i) s += xs[bd][(i * 9 + cl) * ND + n];
        } else {
          const int br = (r / 3) * 3, bc = (cl / 3) * 3;
          for (int i = 0; i < 3; ++i)
            for (int j = 0; j < 3; ++j) s += xs[bd][((br + i) * 9 + bc + j) * ND + n];
        }
        fs[bd][e][u] = s;
      }
    }
    __syncthreads();

    // ---- layer 1: a = bias; a += f[i]*W1[i][j] ascending i ----
    {
      float a[8][2];
      const float2 bv = *(const float2*)&p.Bb[0][j0];
#pragma unroll
      for (int s = 0; s < 8; ++s) { a[s][0] = bv.x; a[s][1] = bv.y; }
      for (int i = 0; i < 27; ++i) {
        const float2 w = *(const float2*)&p.W[0][i * HD + j0];
#pragma unroll
        for (int s = 0; s < 8; ++s) {
          const float f = fs[s >> 2][s & 3][i];
          a[s][0] += f * w.x;
          a[s][1] += f * w.y;
        }
      }
#pragma unroll
      for (int s = 0; s < 8; ++s) {
        hbuf[0][s * HD + j0] = fmaxf(a[s][0], 0.f);
        hbuf[0][s * HD + j0 + 1] = fmaxf(a[s][1], 0.f);
      }
    }
    __syncthreads();

    // ---- layers 2..9: GEMV, acc=0, ascending k, +bias, relu ----
    int cur = 0;
    for (int l = 1; l <= 8; ++l) {
      const float* __restrict__ Wl = p.W[l];
      const float* hin = hbuf[cur];
      float* hout = hbuf[cur ^ 1];
      float a[8][2];
#pragma unroll
      for (int s = 0; s < 8; ++s) { a[s][0] = 0.f; a[s][1] = 0.f; }
      for (int k4 = 0; k4 < HD / 4; ++k4) {
        float hv[8][4];
#pragma unroll
        for (int s = 0; s < 8; ++s) {
          const float4 t4 = *(const float4*)&hin[s * HD + k4 * 4];
          hv[s][0] = t4.x; hv[s][1] = t4.y; hv[s][2] = t4.z; hv[s][3] = t4.w;
        }
#pragma unroll
        for (int kk = 0; kk < 4; ++kk) {
          const float2 w = *(const float2*)&Wl[(k4 * 4 + kk) * HD + j0];
#pragma unroll
          for (int s = 0; s < 8; ++s) {
            a[s][0] += hv[s][kk] * w.x;
            a[s][1] += hv[s][kk] * w.y;
          }
        }
      }
      const float2 bv = *(const float2*)&p.Bb[l][j0];
#pragma unroll
      for (int s = 0; s < 8; ++s) {
        hout[s * HD + j0] = fmaxf(a[s][0] + bv.x, 0.f);
        hout[s * HD + j0 + 1] = fmaxf(a[s][1] + bv.y, 0.f);
      }
      __syncthreads();
      cur ^= 1;
    }
    // after 8 layers, h9 is in hbuf[0]

    // ---- final: layer 10 + softmax + per-slot max (wave per slot) ----
    {
      const float* h9 = hbuf[0];
      const int wv = tid >> 6, lane = tid & 63;
      for (int s = wv; s < 8; s += 4) {
        float acc[ND];
#pragma unroll
        for (int j = 0; j < ND; ++j) acc[j] = 0.f;
#pragma unroll
        for (int i = 0; i < 8; ++i) {
          const int k = lane + 64 * i;
          const float hvv = h9[s * HD + k];
#pragma unroll
          for (int j = 0; j < ND; ++j) acc[j] += hvv * W10s[k * ND + j];
        }
#pragma unroll
        for (int j = 0; j < ND; ++j) {
#pragma unroll
          for (int off = 32; off >= 1; off >>= 1)
            acc[j] += __shfl_xor(acc[j], off, 64);
        }
        const int bd = s >> 2, e = s & 3;
        if (lane == 0 && e < eCnt[bd]) {
          float lgt[ND];
#pragma unroll
          for (int j = 0; j < ND; ++j) lgt[j] = acc[j] + p.Bb[9][j];
          float mx = lgt[0];
          for (int j = 1; j < ND; ++j) mx = fmaxf(mx, lgt[j]);
          float e2[ND], sm = 0.f;
          for (int j = 0; j < ND; ++j) {
            e2[j] = expf(lgt[j] - mx);
            sm += e2[j];
          }
          float pr[ND];
          for (int j = 0; j < ND; ++j) pr[j] = e2[j] / sm;
          const int q = lst[bd][e];
          float best = pr[0];
          int pos = 0;
          for (int j = 1; j < ND; ++j)
            if (pr[j] > best) { best = pr[j]; pos = j; }  // first-index tie-break
          float* dst = p.xpred + ((b0 + bd) * NN + q) * ND;
          for (int j = 0; j < ND; ++j) dst[j] = pr[j];
          sMax[s] = best;
          sPos[s] = pos;
        }
      }
    }
    __syncthreads();

    // ---- update: most confident slot per board (strict >, lowest q wins) ----
    if (tid < 2) {
      const int c = eCnt[tid];
      if (c > 0) {
        float best = sMax[tid * 4];
        int bj = 0;
        for (int j = 1; j < c; ++j) {
          const float v = sMax[tid * 4 + j];
          if (v > best) { best = v; bj = j; }
        }
        const int q = lst[tid][bj], pos = sPos[tid * 4 + bj];
        xs[tid][q * ND + pos] = 1.0f;
      }
    }
    __syncthreads();
  }

  // ---- write final board state (output 2) ----
  for (int bd = 0; bd < 2; ++bd)
    for (int i = tid; i < BND; i += TPB)
      p.xcur[(b0 + bd) * BND + i] = xs[bd][i];
}

extern "C" void kernel_launch(void* const* d_in, const int* in_sizes, int n_in,
                              void* d_out, int out_size, void* d_ws, size_t ws_size,
                              hipStream_t stream) {
  Params prm;
  prm.x_in = (const float*)d_in[0];
  for (int i = 0; i < 10; ++i) {
    prm.W[i] = (const float*)d_in[2 + 2 * i];
    prm.Bb[i] = (const float*)d_in[3 + 2 * i];
  }
  prm.n_it = (const int*)d_in[22];
  prm.xpred = (float*)d_out;
  prm.xcur = prm.xpred + XTOT;

  fused<<<dim3(NBLK), dim3(TPB), 0, stream>>>(prm);
}

// Round 4
// 910.617 us; speedup vs baseline: 8.2862x; 1.6400x over previous
//
#include <hip/hip_runtime.h>

// Sudoku solver: ONE kernel, zero grid syncs. Each block owns 2 boards and
// runs the whole 4-iteration pipeline block-locally (boards are independent).
// Round-4 changes vs round-3 (which was 1 wave/SIMD, VALUBusy 25%):
//  - TPB 512 (8 waves/block -> 2 waves/SIMD latency hiding), 1 col/thread
//  - slot-interleaved LDS activations h[k][slot]: 1 broadcast b128 = 4 slots
//  - explicit 8-deep weight/LDS prefetch per k-chunk
//  - template<CNT> active-slot specialization (every board has exactly 4-it
//    empties at iter it; dead-slot FMAs skipped)
// Per-output accumulation order (ascending-k single chain, bias-then-relu,
// same final-layer lane+shuffle pattern) is IDENTICAL to the verified
// baseline -> same argmax decisions, same absmax.

#define NN 81
#define ND 9
#define BND 729            // NN*ND
#define HD 512
#define BTSZ 512
#define XTOT (BTSZ * BND)  // 373248
#define NBLK 256           // 2 boards per block
#define TPB 512

struct Params {
  const float* x_in;
  const float* W[10];
  const float* Bb[10];
  const int* n_it;
  float* xpred;
  float* xcur;
};

// layers 2..9: GEMV over slot-interleaved LDS activations.
// hin/hout layout: h[k*8 + bd*4 + e], k in [0,512), bd in {0,1}, e in [0,4)
template <int CNT>
__device__ __forceinline__ void run_layers(const Params& p, int j,
                                           float* bufA, float* bufB) {
  const float* hin = bufA;
  float* hout = bufB;
  for (int l = 1; l <= 8; ++l) {
    const float* __restrict__ Wl = p.W[l];
    float a0[CNT], a1[CNT];
#pragma unroll
    for (int e = 0; e < CNT; ++e) { a0[e] = 0.f; a1[e] = 0.f; }
    for (int k0 = 0; k0 < HD; k0 += 8) {
      float w[8];
#pragma unroll
      for (int kk = 0; kk < 8; ++kk) w[kk] = Wl[(k0 + kk) * HD + j];
      if constexpr (CNT > 2) {
        float4 hA[8], hB[8];
#pragma unroll
        for (int kk = 0; kk < 8; ++kk) {
          hA[kk] = *(const float4*)&hin[(k0 + kk) * 8];
          hB[kk] = *(const float4*)&hin[(k0 + kk) * 8 + 4];
        }
#pragma unroll
        for (int kk = 0; kk < 8; ++kk) {
          const float ha[4] = {hA[kk].x, hA[kk].y, hA[kk].z, hA[kk].w};
          const float hb[4] = {hB[kk].x, hB[kk].y, hB[kk].z, hB[kk].w};
#pragma unroll
          for (int e = 0; e < CNT; ++e) {
            a0[e] += ha[e] * w[kk];
            a1[e] += hb[e] * w[kk];
          }
        }
      } else {
        float2 hA[8], hB[8];
#pragma unroll
        for (int kk = 0; kk < 8; ++kk) {
          hA[kk] = *(const float2*)&hin[(k0 + kk) * 8];
          hB[kk] = *(const float2*)&hin[(k0 + kk) * 8 + 4];
        }
#pragma unroll
        for (int kk = 0; kk < 8; ++kk) {
          const float ha[2] = {hA[kk].x, hA[kk].y};
          const float hb[2] = {hB[kk].x, hB[kk].y};
#pragma unroll
          for (int e = 0; e < CNT; ++e) {
            a0[e] += ha[e] * w[kk];
            a1[e] += hb[e] * w[kk];
          }
        }
      }
    }
    const float bj = p.Bb[l][j];
    float o0[4] = {0.f, 0.f, 0.f, 0.f}, o1[4] = {0.f, 0.f, 0.f, 0.f};
#pragma unroll
    for (int e = 0; e < CNT; ++e) { o0[e] = a0[e] + bj; o1[e] = a1[e] + bj; }
    float4 v0, v1;
    v0.x = fmaxf(o0[0], 0.f); v0.y = fmaxf(o0[1], 0.f);
    v0.z = fmaxf(o0[2], 0.f); v0.w = fmaxf(o0[3], 0.f);
    v1.x = fmaxf(o1[0], 0.f); v1.y = fmaxf(o1[1], 0.f);
    v1.z = fmaxf(o1[2], 0.f); v1.w = fmaxf(o1[3], 0.f);
    *(float4*)&hout[j * 8] = v0;
    *(float4*)&hout[j * 8 + 4] = v1;
    __syncthreads();
    const float* t = hin; hin = hout; hout = (float*)t;
  }
}

__global__ __launch_bounds__(TPB, 2) void fused(Params p) {
  const int tid = threadIdx.x;
  const int bid = blockIdx.x;
  const int b0 = bid * 2;

  __shared__ __align__(16) float hbufA[HD * 8];  // 16 KB ping
  __shared__ __align__(16) float hbufB[HD * 8];  // 16 KB pong
  __shared__ __align__(16) float W10s[HD * ND];  // 18 KB
  __shared__ float xs[2][BND + 3];
  __shared__ float fs[2][4][28];
  __shared__ float sMax[8];
  __shared__ int sPos[8];
  __shared__ int ef[2][NN + 7];
  __shared__ int lst[2][4];
  __shared__ int eCnt[2];

  for (int i = tid; i < HD * ND; i += TPB) W10s[i] = p.W[9][i];
  for (int bd = 0; bd < 2; ++bd)
    for (int i = tid; i < BND; i += TPB) {
      const float v = p.x_in[(b0 + bd) * BND + i];
      xs[bd][i] = v;
      p.xpred[(b0 + bd) * BND + i] = v;
    }
  const int nIters = p.n_it[0];
  __syncthreads();

  const int j = tid;  // output column owned by this thread

  for (int it = 0; it < 4; ++it) {
    if (it >= nIters) break;

    // ---- empty flags ----
    if (tid < 2 * NN) {
      const int bd = tid / NN, q = tid - bd * NN;
      float s = 0.f;
#pragma unroll
      for (int n = 0; n < ND; ++n) s += xs[bd][q * ND + n];
      ef[bd][q] = (s == 0.0f) ? 1 : 0;
    }
    __syncthreads();
    if (tid < 2) {
      int c = 0;
      for (int q = 0; q < NN; ++q)
        if (ef[tid][q] && c < 4) lst[tid][c++] = q;  // ascending q
      eCnt[tid] = c;
    }
    __syncthreads();

    // ---- features (zero for inactive slots) ----
    {
      const int sl = tid >> 5, u = tid & 31;
      if (sl < 8) {
        const int bd = sl >> 2, e = sl & 3;
        if (u < 28) fs[bd][e][u] = 0.0f;
        if (u < 27 && e < eCnt[bd]) {
          const int q = lst[bd][e], t = u / 9, n = u - t * 9;
          const int r = q / 9, cl = q - r * 9;
          float s = 0.f;
          if (t == 0) {
            for (int i = 0; i < 9; ++i) s += xs[bd][(r * 9 + i) * ND + n];
          } else if (t == 1) {
            for (int i = 0; i < 9; ++i) s += xs[bd][(i * 9 + cl) * ND + n];
          } else {
            const int br = (r / 3) * 3, bc = (cl / 3) * 3;
            for (int i = 0; i < 3; ++i)
              for (int jj = 0; jj < 3; ++jj)
                s += xs[bd][((br + i) * 9 + bc + jj) * ND + n];
          }
          fs[bd][e][u] = s;
        }
      }
    }
    __syncthreads();

    // ---- layer 1: bias + ascending-i chain, write slot-interleaved ----
    {
      float a[2][4];
      const float b1 = p.Bb[0][j];
#pragma unroll
      for (int bd = 0; bd < 2; ++bd)
#pragma unroll
        for (int e = 0; e < 4; ++e) a[bd][e] = b1;
      for (int i = 0; i < 27; ++i) {
        const float w = p.W[0][i * HD + j];
#pragma unroll
        for (int bd = 0; bd < 2; ++bd)
#pragma unroll
          for (int e = 0; e < 4; ++e) a[bd][e] += fs[bd][e][i] * w;
      }
      float4 v0, v1;
      v0.x = fmaxf(a[0][0], 0.f); v0.y = fmaxf(a[0][1], 0.f);
      v0.z = fmaxf(a[0][2], 0.f); v0.w = fmaxf(a[0][3], 0.f);
      v1.x = fmaxf(a[1][0], 0.f); v1.y = fmaxf(a[1][1], 0.f);
      v1.z = fmaxf(a[1][2], 0.f); v1.w = fmaxf(a[1][3], 0.f);
      *(float4*)&hbufA[j * 8] = v0;
      *(float4*)&hbufA[j * 8 + 4] = v1;
    }
    __syncthreads();

    // ---- layers 2..9, specialized on active slot count ----
    const int cm = max(eCnt[0], eCnt[1]);
    if (cm == 4) run_layers<4>(p, j, hbufA, hbufB);
    else if (cm == 3) run_layers<3>(p, j, hbufA, hbufB);
    else if (cm == 2) run_layers<2>(p, j, hbufA, hbufB);
    else if (cm == 1) run_layers<1>(p, j, hbufA, hbufB);
    // after 8 layers (even # of swaps), h9 is in hbufA

    // ---- final: layer 10 + softmax + per-slot max (wave per slot) ----
    if (cm > 0) {
      const int s = tid >> 6, lane = tid & 63;
      const int bd = s >> 2, e = s & 3;
      if (e < eCnt[bd]) {
        float acc[ND];
#pragma unroll
        for (int jj = 0; jj < ND; ++jj) acc[jj] = 0.f;
#pragma unroll
        for (int i = 0; i < 8; ++i) {
          const int k = lane + 64 * i;
          const float hvv = hbufA[k * 8 + s];
#pragma unroll
          for (int jj = 0; jj < ND; ++jj) acc[jj] += hvv * W10s[k * ND + jj];
        }
#pragma unroll
        for (int jj = 0; jj < ND; ++jj) {
#pragma unroll
          for (int off = 32; off >= 1; off >>= 1)
            acc[jj] += __shfl_xor(acc[jj], off, 64);
        }
        if (lane == 0) {
          float lgt[ND];
#pragma unroll
          for (int jj = 0; jj < ND; ++jj) lgt[jj] = acc[jj] + p.Bb[9][jj];
          float mx = lgt[0];
          for (int jj = 1; jj < ND; ++jj) mx = fmaxf(mx, lgt[jj]);
          float e2[ND], sm = 0.f;
          for (int jj = 0; jj < ND; ++jj) {
            e2[jj] = expf(lgt[jj] - mx);
            sm += e2[jj];
          }
          float pr[ND];
          for (int jj = 0; jj < ND; ++jj) pr[jj] = e2[jj] / sm;
          const int q = lst[bd][e];
          float best = pr[0];
          int pos = 0;
          for (int jj = 1; jj < ND; ++jj)
            if (pr[jj] > best) { best = pr[jj]; pos = jj; }  // first-index tie
          float* dst = p.xpred + ((b0 + bd) * NN + q) * ND;
          for (int jj = 0; jj < ND; ++jj) dst[jj] = pr[jj];
          sMax[s] = best;
          sPos[s] = pos;
        }
      }
    }
    __syncthreads();

    // ---- update: most confident slot per board (strict >, lowest q) ----
    if (tid < 2) {
      const int c = eCnt[tid];
      if (c > 0) {
        float best = sMax[tid * 4];
        int bj = 0;
        for (int jj = 1; jj < c; ++jj) {
          const float v = sMax[tid * 4 + jj];
          if (v > best) { best = v; bj = jj; }
        }
        const int q = lst[tid][bj], pos = sPos[tid * 4 + bj];
        xs[tid][q * ND + pos] = 1.0f;
      }
    }
    __syncthreads();
  }

  // ---- write final board state (output 2) ----
  for (int bd = 0; bd < 2; ++bd)
    for (int i = tid; i < BND; i += TPB)
      p.xcur[(b0 + bd) * BND + i] = xs[bd][i];
}

extern "C" void kernel_launch(void* const* d_in, const int* in_sizes, int n_in,
                              void* d_out, int out_size, void* d_ws, size_t ws_size,
                              hipStream_t stream) {
  Params prm;
  prm.x_in = (const float*)d_in[0];
  for (int i = 0; i < 10; ++i) {
    prm.W[i] = (const float*)d_in[2 + 2 * i];
    prm.Bb[i] = (const float*)d_in[3 + 2 * i];
  }
  prm.n_it = (const int*)d_in[22];
  prm.xpred = (float*)d_out;
  prm.xcur = prm.xpred + XTOT;

  fused<<<dim3(NBLK), dim3(TPB), 0, stream>>>(prm);
}